// Round 2
// baseline (363.599 us; speedup 1.0000x reference)
//
#include <hip/hip_runtime.h>

typedef __attribute__((ext_vector_type(8))) __bf16 bf16x8;
typedef __attribute__((ext_vector_type(4))) float floatx4;

#define M_TOT 256
#define K_TOT 5120
#define N_TOT 13824
#define NBLK  320      // K/16
#define BM    128
#define BN    64
#define BK    64
#define NSTEP 80       // K/BK

#define GLOAD_LDS16(g, l)                                                     \
  __builtin_amdgcn_global_load_lds(                                           \
      (const __attribute__((address_space(1))) void*)(g),                     \
      (__attribute__((address_space(3))) void*)(l), 16, 0, 0)

static __device__ __forceinline__ float bf16r(float v) { return (float)(__bf16)v; }

static __device__ __forceinline__ float fp4round(float v) {
  float a = fabsf(v), q;
  if      (a < 0.25f) q = 0.0f;
  else if (a < 0.75f) q = 0.5f;
  else if (a < 1.25f) q = 1.0f;
  else if (a < 1.75f) q = 1.5f;
  else if (a < 2.5f)  q = 2.0f;
  else if (a < 3.5f)  q = 3.0f;
  else if (a < 5.0f)  q = 4.0f;
  else                q = 6.0f;
  return copysignf(q, v);
}

// round f (in [0,448]) to fp8 e4m3fn, RNE — exact pow2 arithmetic
static __device__ __forceinline__ float cvt_e4m3(float f) {
  if (f < 0.015625f) return rintf(f * 512.0f) * 0.001953125f;  // subnormal, q=2^-9
  int e = (int)(__float_as_uint(f) >> 23) - 127;
  float q = __uint_as_float((unsigned)(e - 3 + 127) << 23);    // 2^(e-3)
  return rintf(f / q) * q;                                     // exact div/mul by pow2
}

// ---------------- kernel 1: global amax of bf16(x) ----------------
__global__ void k_amax(const float* __restrict__ x, unsigned* __restrict__ amax_bits) {
  int i = blockIdx.x * blockDim.x + threadIdx.x;   // one float4 per thread, exact cover
  float4 v = ((const float4*)x)[i];
  float m = fmaxf(fmaxf(fabsf(bf16r(v.x)), fabsf(bf16r(v.y))),
                  fmaxf(fabsf(bf16r(v.z)), fabsf(bf16r(v.w))));
#pragma unroll
  for (int off = 32; off; off >>= 1) m = fmaxf(m, __shfl_xor(m, off));
  if ((threadIdx.x & 63) == 0) atomicMax(amax_bits, __float_as_uint(m));
}

// ------- kernel 2: activation nvfp4 quant, folded to bf16 a_u = q*s -------
__global__ void k_aquant(const float* __restrict__ x,
                         const unsigned* __restrict__ amax_bits,
                         __bf16* __restrict__ au) {
  int idx = blockIdx.x * blockDim.x + threadIdx.x;  // 0..81919 (m*320+b)
  int m = idx / NBLK;
  int b = idx - m * NBLK;
  float amax = __uint_as_float(*amax_bits);
  float gs  = 2688.0f / amax;   // (448*6)/amax, matches ref op order
  float gs6 = gs / 6.0f;
  const float4* xp = (const float4*)(x + m * K_TOT + b * 16);
  float4 v0 = xp[0], v1 = xp[1], v2 = xp[2], v3 = xp[3];
  float xv[16];
  xv[0]=bf16r(v0.x); xv[1]=bf16r(v0.y); xv[2]=bf16r(v0.z); xv[3]=bf16r(v0.w);
  xv[4]=bf16r(v1.x); xv[5]=bf16r(v1.y); xv[6]=bf16r(v1.z); xv[7]=bf16r(v1.w);
  xv[8]=bf16r(v2.x); xv[9]=bf16r(v2.y); xv[10]=bf16r(v2.z); xv[11]=bf16r(v2.w);
  xv[12]=bf16r(v3.x); xv[13]=bf16r(v3.y); xv[14]=bf16r(v3.z); xv[15]=bf16r(v3.w);
  float am = 0.f;
#pragma unroll
  for (int j = 0; j < 16; ++j) am = fmaxf(am, fabsf(xv[j]));
  float s = cvt_e4m3(fminf(am * gs6, 448.0f));
  float g = gs / ((s == 0.f) ? 1.f : s);
  bf16x8 p0, p1;
#pragma unroll
  for (int j = 0; j < 8; ++j) p0[j] = (__bf16)(fp4round(xv[j] * g) * s);      // exact in bf16
#pragma unroll
  for (int j = 0; j < 8; ++j) p1[j] = (__bf16)(fp4round(xv[8 + j] * g) * s);
  bf16x8* dst = (bf16x8*)(au + (size_t)idx * 16);
  dst[0] = p0; dst[1] = p1;
}

// ---------------- kernel 3: bf16 MFMA GEMM, fused weight dequant ----------------
// BM=128, BN=64, BK=64, 256 thr (4 waves: 2M x 2N), wave tile 64x32.
// A double-buffered in LDS via global_load_lds (swizzled source);
// B (weights) loaded straight global->reg as exact MFMA fragments, dequant in reg.
__global__ __launch_bounds__(256, 4) void k_gemm(
    const __bf16* __restrict__ au,      // [256][5120] bf16 (scales folded)
    const float*  __restrict__ w,       // [N][K] fp4 values in f32
    const float*  __restrict__ wsc,     // [N][320] fp8-representable scales
    const unsigned* __restrict__ amax_bits,
    const float*  __restrict__ wgs,     // scalar
    const float*  __restrict__ bias,    // [N]
    float* __restrict__ out)            // [256][13824]
{
  __shared__ __bf16 Ab[2][BM * BK];     // 2 x 16 KB

  const int tid  = threadIdx.x;
  const int lane = tid & 63;
  const int wv   = tid >> 6;     // 0..3
  const int wm   = wv >> 1;      // 0..1 (64-row group)
  const int wn   = wv & 1;       // 0..1 (32-col group)

  // bijective XCD swizzle (432 % 8 == 0): the two m-blocks of one weight
  // panel are 8 apart in blockIdx -> same XCD under round-robin dispatch.
  const int wgid = (blockIdx.x & 7) * 54 + (blockIdx.x >> 3);
  const int n0   = (wgid >> 1) * BN;
  const int m0   = (wgid & 1) * BM;

  const int hi  = lane >> 4;     // 0..3 (k-chunk of 8 within 32)
  const int r15 = lane & 15;
  const int sw  = (lane & 7) << 4;

  // A staging: wave wv covers rows wv*32 + i*8 + (lane>>3); LDS layout
  // byte = row*128 + (chunk ^ (row&7))*16 achieved via pre-swizzled source.
  const int arow = wv * 32 + (lane >> 3);
  const int acol = 8 * ((lane & 7) ^ (lane >> 3));

  // B: per-lane fragment pointers (rows = output cols)
  const float* wrow0  = w + (size_t)(n0 + wn * 32 + r15) * K_TOT + hi * 8;
  const float* wrow1  = wrow0 + (size_t)16 * K_TOT;
  const float* wsrow0 = wsc + (size_t)(n0 + wn * 32 + r15) * NBLK + (hi >> 1);
  const float* wsrow1 = wsrow0 + (size_t)16 * NBLK;

  floatx4 acc[4][2];
#pragma unroll
  for (int fm = 0; fm < 4; ++fm)
#pragma unroll
    for (int fn = 0; fn < 2; ++fn) acc[fm][fn] = (floatx4){0.f, 0.f, 0.f, 0.f};

  float4 braw[2][2][2];  // [fn][kk][half]
  float  bsc[2][2];

  auto issueA = [&](int t, int buf) {
    const __bf16* src = au + (size_t)(m0 + arow) * K_TOT + t * BK + acol;
    char* dst = (char*)(&Ab[buf][0]) + wv * 4096;
#pragma unroll
    for (int i = 0; i < 4; ++i)
      GLOAD_LDS16(src + (size_t)i * 8 * K_TOT, dst + i * 1024);
  };
  auto loadB = [&](int t) {
#pragma unroll
    for (int kk = 0; kk < 2; ++kk) {
      const float* p0 = wrow0 + t * BK + kk * 32;
      const float* p1 = wrow1 + t * BK + kk * 32;
      braw[0][kk][0] = *(const float4*)p0;
      braw[0][kk][1] = *(const float4*)(p0 + 4);
      braw[1][kk][0] = *(const float4*)p1;
      braw[1][kk][1] = *(const float4*)(p1 + 4);
      bsc[0][kk] = wsrow0[t * 4 + kk * 2];
      bsc[1][kk] = wsrow1[t * 4 + kk * 2];
    }
  };

  // prologue
  issueA(0, 0);
  loadB(0);
  __syncthreads();

  int buf = 0;
#pragma unroll 1
  for (int t = 0; t < NSTEP; ++t) {
    // dequant current B tile to bf16 fragments (exact in bf16)
    bf16x8 bfr[2][2];
#pragma unroll
    for (int fn = 0; fn < 2; ++fn)
#pragma unroll
      for (int kk = 0; kk < 2; ++kk) {
        float s = bsc[fn][kk];
        float4 a = braw[fn][kk][0], b = braw[fn][kk][1];
        bf16x8 v;
        v[0] = (__bf16)(a.x * s); v[1] = (__bf16)(a.y * s);
        v[2] = (__bf16)(a.z * s); v[3] = (__bf16)(a.w * s);
        v[4] = (__bf16)(b.x * s); v[5] = (__bf16)(b.y * s);
        v[6] = (__bf16)(b.z * s); v[7] = (__bf16)(b.w * s);
        bfr[fn][kk] = v;
      }
    // issue next tile's loads so they fly during compute + barrier
    if (t + 1 < NSTEP) { issueA(t + 1, buf ^ 1); loadB(t + 1); }
    // compute from A LDS + B regs
    char* pA = (char*)(&Ab[buf][0]);
#pragma unroll
    for (int kk = 0; kk < 2; ++kk) {
      const int cb = kk * 64 + hi * 16;
      bf16x8 af[4];
#pragma unroll
      for (int fm = 0; fm < 4; ++fm)
        af[fm] = *(const bf16x8*)(pA + (wm * 64 + fm * 16 + r15) * 128 + (cb ^ sw));
#pragma unroll
      for (int fm = 0; fm < 4; ++fm)
#pragma unroll
        for (int fn = 0; fn < 2; ++fn)
          acc[fm][fn] = __builtin_amdgcn_mfma_f32_16x16x32_bf16(af[fm], bfr[fn][kk], acc[fm][fn], 0, 0, 0);
    }
    __syncthreads();
    buf ^= 1;
  }

  // epilogue
  float amax = __uint_as_float(*amax_bits);
  float a_gs = 2688.0f / amax;
  float alpha = 1.0f / (a_gs * wgs[0]);
#pragma unroll
  for (int fm = 0; fm < 4; ++fm) {
#pragma unroll
    for (int fn = 0; fn < 2; ++fn) {
      int mrow = m0 + wm * 64 + fm * 16 + hi * 4;
      int ncol = n0 + wn * 32 + fn * 16 + r15;
      float bb = bias[ncol];
#pragma unroll
      for (int j = 0; j < 4; ++j)
        out[(size_t)(mrow + j) * N_TOT + ncol] = acc[fm][fn][j] * alpha + bb;
    }
  }
}

extern "C" void kernel_launch(void* const* d_in, const int* in_sizes, int n_in,
                              void* d_out, int out_size, void* d_ws, size_t ws_size,
                              hipStream_t stream) {
  const float* x    = (const float*)d_in[0];
  const float* wq   = (const float*)d_in[1];
  const float* wsc  = (const float*)d_in[2];
  const float* wgs  = (const float*)d_in[3];
  const float* bias = (const float*)d_in[4];
  float* out = (float*)d_out;

  unsigned* amax = (unsigned*)d_ws;
  __bf16* au = (__bf16*)((char*)d_ws + 256);   // 2.62 MB scratch

  hipMemsetAsync(d_ws, 0, 4, stream);
  k_amax<<<dim3(M_TOT * K_TOT / 4 / 256), dim3(256), 0, stream>>>(x, amax);
  k_aquant<<<dim3(M_TOT * NBLK / 256), dim3(256), 0, stream>>>(x, amax, au);
  k_gemm<<<dim3((N_TOT / BN) * 2), dim3(256), 0, stream>>>(au, wq, wsc, amax, wgs, bias, out);
}

// Round 3
// 209.581 us; speedup vs baseline: 1.7349x; 1.7349x over previous
//
#include <hip/hip_runtime.h>

typedef __attribute__((ext_vector_type(8))) __bf16 bf16x8;
typedef __attribute__((ext_vector_type(4))) float floatx4;

#define M_TOT 256
#define K_TOT 5120
#define N_TOT 13824
#define NBLK  320      // K/16
#define BN    64
#define BK    64
#define KSPLIT 4
#define KCH   1280     // K / KSPLIT
#define NSTEP 20       // KCH / BK

#define GLOAD_LDS16(g, l)                                                     \
  __builtin_amdgcn_global_load_lds(                                           \
      (const __attribute__((address_space(1))) void*)(g),                     \
      (__attribute__((address_space(3))) void*)(l), 16, 0, 0)

static __device__ __forceinline__ float bf16r(float v) { return (float)(__bf16)v; }

static __device__ __forceinline__ float fp4round(float v) {
  float a = fabsf(v), q;
  if      (a < 0.25f) q = 0.0f;
  else if (a < 0.75f) q = 0.5f;
  else if (a < 1.25f) q = 1.0f;
  else if (a < 1.75f) q = 1.5f;
  else if (a < 2.5f)  q = 2.0f;
  else if (a < 3.5f)  q = 3.0f;
  else if (a < 5.0f)  q = 4.0f;
  else                q = 6.0f;
  return copysignf(q, v);
}

// round f (in [0,448]) to fp8 e4m3fn, RNE — exact pow2 arithmetic
static __device__ __forceinline__ float cvt_e4m3(float f) {
  if (f < 0.015625f) return rintf(f * 512.0f) * 0.001953125f;  // subnormal, q=2^-9
  int e = (int)(__float_as_uint(f) >> 23) - 127;
  float q = __uint_as_float((unsigned)(e - 3 + 127) << 23);    // 2^(e-3)
  return rintf(f / q) * q;                                     // exact div/mul by pow2
}

// ---------------- kernel 1: global amax of bf16(x) ----------------
__global__ void k_amax(const float* __restrict__ x, unsigned* __restrict__ amax_bits) {
  int i = blockIdx.x * blockDim.x + threadIdx.x;   // one float4 per thread, exact cover
  float4 v = ((const float4*)x)[i];
  float m = fmaxf(fmaxf(fabsf(bf16r(v.x)), fabsf(bf16r(v.y))),
                  fmaxf(fabsf(bf16r(v.z)), fabsf(bf16r(v.w))));
#pragma unroll
  for (int off = 32; off; off >>= 1) m = fmaxf(m, __shfl_xor(m, off));
  if ((threadIdx.x & 63) == 0) atomicMax(amax_bits, __float_as_uint(m));
}

// ------- kernel 2: activation nvfp4 quant, folded to bf16 a_u = q*s -------
__global__ void k_aquant(const float* __restrict__ x,
                         const unsigned* __restrict__ amax_bits,
                         __bf16* __restrict__ au) {
  int idx = blockIdx.x * blockDim.x + threadIdx.x;  // 0..81919 (m*320+b)
  int m = idx / NBLK;
  int b = idx - m * NBLK;
  float amax = __uint_as_float(*amax_bits);
  float gs  = 2688.0f / amax;   // (448*6)/amax, matches ref op order
  float gs6 = gs / 6.0f;
  const float4* xp = (const float4*)(x + m * K_TOT + b * 16);
  float4 v0 = xp[0], v1 = xp[1], v2 = xp[2], v3 = xp[3];
  float xv[16];
  xv[0]=bf16r(v0.x); xv[1]=bf16r(v0.y); xv[2]=bf16r(v0.z); xv[3]=bf16r(v0.w);
  xv[4]=bf16r(v1.x); xv[5]=bf16r(v1.y); xv[6]=bf16r(v1.z); xv[7]=bf16r(v1.w);
  xv[8]=bf16r(v2.x); xv[9]=bf16r(v2.y); xv[10]=bf16r(v2.z); xv[11]=bf16r(v2.w);
  xv[12]=bf16r(v3.x); xv[13]=bf16r(v3.y); xv[14]=bf16r(v3.z); xv[15]=bf16r(v3.w);
  float am = 0.f;
#pragma unroll
  for (int j = 0; j < 16; ++j) am = fmaxf(am, fabsf(xv[j]));
  float s = cvt_e4m3(fminf(am * gs6, 448.0f));
  float g = gs / ((s == 0.f) ? 1.f : s);
  bf16x8 p0, p1;
#pragma unroll
  for (int j = 0; j < 8; ++j) p0[j] = (__bf16)(fp4round(xv[j] * g) * s);      // exact in bf16
#pragma unroll
  for (int j = 0; j < 8; ++j) p1[j] = (__bf16)(fp4round(xv[8 + j] * g) * s);
  bf16x8* dst = (bf16x8*)(au + (size_t)idx * 16);
  dst[0] = p0; dst[1] = p1;
}

// ---------------- kernel 3: bf16 MFMA GEMM, fused weight dequant, split-K ----------------
// BM=256 (all M), BN=64, BK=64, 512 thr (8 waves: 4M x 2N), wave tile 64x32.
// Split-K=4: each block does K-chunk of 1280, accumulates into out via f32 atomics.
__global__ __launch_bounds__(512, 4) void k_gemm(
    const __bf16* __restrict__ au,      // [256][5120] bf16 (scales folded)
    const float*  __restrict__ w,       // [N][K] fp4 values in f32
    const float*  __restrict__ wsc,     // [N][320] fp8-representable scales
    const unsigned* __restrict__ amax_bits,
    const float*  __restrict__ wgs,     // scalar
    const float*  __restrict__ bias,    // [N]
    float* __restrict__ out)            // [256][13824], pre-zeroed
{
  __shared__ __bf16 Ab[2][M_TOT * BK];  // 2 x 32 KB
  __shared__ __bf16 Bb[2][BN * BK];     // 2 x 8 KB

  const int tid  = threadIdx.x;
  const int lane = tid & 63;
  const int wv   = tid >> 6;     // 0..7
  const int wm   = wv >> 1;      // 0..3 (64-row group)
  const int wn   = wv & 1;       // 0..1 (32-col group)

  const int s     = blockIdx.x & (KSPLIT - 1);
  const int n0    = (blockIdx.x >> 2) * BN;
  const int kbase = s * KCH;

  // A staging: global_load_lds, linear LDS dest; source pre-swizzled so that
  // LDS holds layout byte = row*128 + (colbytes ^ ((row&7)<<4)).
  const int arow  = wv * 32 + (lane >> 3);           // + i*8 per call
  const int acolp = 8 * ((lane & 7) ^ (lane >> 3));  // pre-swizzled k offset

  // B staging: 8 f32 per thread, one scale, swizzled ds_write_b128
  const int brow = tid >> 3;    // 0..63
  const int bcg  = tid & 7;     // 8-elem group
  const float* wp  = w   + (size_t)(n0 + brow) * K_TOT + kbase + bcg * 8;
  const float* wsp = wsc + (size_t)(n0 + brow) * NBLK + s * (KCH / 16) + (bcg >> 1);
  const int bdst = brow * 128 + ((bcg * 16) ^ ((brow & 7) << 4));

  // fragment read offsets
  const int sw    = (lane & 7) << 4;
  const int hi    = lane >> 4;
  const int r15   = lane & 15;

  floatx4 acc[4][2];
#pragma unroll
  for (int fm = 0; fm < 4; ++fm)
#pragma unroll
    for (int fn = 0; fn < 2; ++fn) acc[fm][fn] = (floatx4){0.f, 0.f, 0.f, 0.f};

  float4 bv0, bv1; float bs;

  auto issueA = [&](int t, int buf) {
    const __bf16* src = au + (size_t)arow * K_TOT + kbase + t * BK + acolp;
    char* dst = (char*)(&Ab[buf][0]) + wv * 4096;
#pragma unroll
    for (int i = 0; i < 4; ++i)
      GLOAD_LDS16(src + (size_t)i * 8 * K_TOT, dst + i * 1024);
  };
  auto loadB = [&](int t) {
    const float* p = wp + t * BK;
    bv0 = *(const float4*)p;
    bv1 = *(const float4*)(p + 4);
    bs  = wsp[t * 4];
  };
  auto writeB = [&](int buf) {
    float vv[8] = {bv0.x, bv0.y, bv0.z, bv0.w, bv1.x, bv1.y, bv1.z, bv1.w};
    bf16x8 pk;
#pragma unroll
    for (int j = 0; j < 8; ++j) pk[j] = (__bf16)(vv[j] * bs);  // exact in bf16
    *(bf16x8*)((char*)(&Bb[buf][0]) + bdst) = pk;
  };
  auto compute = [&](int buf) {
    char* pA = (char*)(&Ab[buf][0]);
    char* pB = (char*)(&Bb[buf][0]);
#pragma unroll
    for (int ss = 0; ss < 2; ++ss) {
      const int cb = ss * 64 + hi * 16;
      bf16x8 af[4], bfr[2];
#pragma unroll
      for (int fm = 0; fm < 4; ++fm)
        af[fm] = *(const bf16x8*)(pA + (wm * 64 + fm * 16 + r15) * 128 + (cb ^ sw));
#pragma unroll
      for (int fn = 0; fn < 2; ++fn)
        bfr[fn] = *(const bf16x8*)(pB + (wn * 32 + fn * 16 + r15) * 128 + (cb ^ sw));
#pragma unroll
      for (int fm = 0; fm < 4; ++fm)
#pragma unroll
        for (int fn = 0; fn < 2; ++fn)
          acc[fm][fn] = __builtin_amdgcn_mfma_f32_16x16x32_bf16(af[fm], bfr[fn], acc[fm][fn], 0, 0, 0);
    }
  };

  // 2-phase pipeline
  int buf = 0;
  issueA(0, 0);
  loadB(0);
  writeB(0);
  __syncthreads();
#pragma unroll 1
  for (int t = 0; t < NSTEP; ++t) {
    if (t + 1 < NSTEP) { issueA(t + 1, buf ^ 1); loadB(t + 1); }
    compute(buf);
    if (t + 1 < NSTEP) writeB(buf ^ 1);
    __syncthreads();
    buf ^= 1;
  }

  // epilogue: atomic accumulate (out pre-zeroed; bias folded into split 0)
  float amax = __uint_as_float(*amax_bits);
  float a_gs = 2688.0f / amax;
  float alpha = 1.0f / (a_gs * wgs[0]);
#pragma unroll
  for (int fm = 0; fm < 4; ++fm) {
#pragma unroll
    for (int fn = 0; fn < 2; ++fn) {
      int mrow = wm * 64 + fm * 16 + hi * 4;
      int ncol = n0 + wn * 32 + fn * 16 + r15;
      float bb = (s == 0) ? bias[ncol] : 0.0f;
#pragma unroll
      for (int j = 0; j < 4; ++j)
        atomicAdd(&out[(size_t)(mrow + j) * N_TOT + ncol],
                  acc[fm][fn][j] * alpha + bb);
    }
  }
}

extern "C" void kernel_launch(void* const* d_in, const int* in_sizes, int n_in,
                              void* d_out, int out_size, void* d_ws, size_t ws_size,
                              hipStream_t stream) {
  const float* x    = (const float*)d_in[0];
  const float* wq   = (const float*)d_in[1];
  const float* wsc  = (const float*)d_in[2];
  const float* wgs  = (const float*)d_in[3];
  const float* bias = (const float*)d_in[4];
  float* out = (float*)d_out;

  unsigned* amax = (unsigned*)d_ws;
  __bf16* au = (__bf16*)((char*)d_ws + 256);   // 2.62 MB scratch

  hipMemsetAsync(d_ws, 0, 4, stream);
  hipMemsetAsync(d_out, 0, (size_t)M_TOT * N_TOT * sizeof(float), stream);
  k_amax<<<dim3(M_TOT * K_TOT / 4 / 256), dim3(256), 0, stream>>>(x, amax);
  k_aquant<<<dim3(M_TOT * NBLK / 256), dim3(256), 0, stream>>>(x, amax, au);
  k_gemm<<<dim3((N_TOT / BN) * KSPLIT), dim3(512), 0, stream>>>(au, wq, wsc, amax, wgs, bias, out);
}